// Round 8
// baseline (288.303 us; speedup 1.0000x reference)
//
#include <hip/hip_runtime.h>
#include <stdint.h>

using bf16x8 = __attribute__((ext_vector_type(8))) __bf16;
using f32x4  = __attribute__((ext_vector_type(4))) float;

#define GLL(g, l) __builtin_amdgcn_global_load_lds(                                  \
    (const __attribute__((address_space(1))) void*)(g),                              \
    (__attribute__((address_space(3))) void*)(l), 16, 0, 0)

__device__ __forceinline__ unsigned short f2bf(float f) {
  unsigned u = __builtin_bit_cast(unsigned, f);
  u += 0x7FFF + ((u >> 16) & 1);   // RNE
  return (unsigned short)(u >> 16);
}
__device__ __forceinline__ float bf2f(unsigned short u) {
  unsigned v = ((unsigned)u) << 16;
  return __builtin_bit_cast(float, v);
}

// ---------- cast fp32 -> bf16 ----------
__global__ __launch_bounds__(256) void cast_kernel(const float* __restrict__ in,
                                                   unsigned short* __restrict__ out, int n4) {
  int i = blockIdx.x * 256 + threadIdx.x;
  if (i >= n4) return;
  float4 v = reinterpret_cast<const float4*>(in)[i];
  ushort4 o;
  o.x = f2bf(v.x); o.y = f2bf(v.y); o.z = f2bf(v.z); o.w = f2bf(v.w);
  reinterpret_cast<ushort4*>(out)[i] = o;
}

// ---------- fused transpose+cast of all 4 weights (one launch) ----------
// y<32: Wq -> Wqkvt[0..2048). y in [32,36): Wk -> rows 2048..2304.
// y in [36,40): Wv -> rows 2304..2560. y in [40,72): Wo -> Wot.
__global__ __launch_bounds__(256) void tcast_all_kernel(const float* __restrict__ Wq,
                                                        const float* __restrict__ Wk,
                                                        const float* __restrict__ Wv,
                                                        const float* __restrict__ Wo,
                                                        unsigned short* __restrict__ Wqkvt,
                                                        unsigned short* __restrict__ Wot) {
  __shared__ float T[64][65];
  const int y = blockIdx.y;
  const float* W;
  unsigned short* Wt;
  int N, n0;
  if (y < 32)      { W = Wq; Wt = Wqkvt;                          N = 2048; n0 = y * 64; }
  else if (y < 36) { W = Wk; Wt = Wqkvt + (size_t)2048 * 2048;    N = 256;  n0 = (y - 32) * 64; }
  else if (y < 40) { W = Wv; Wt = Wqkvt + (size_t)2304 * 2048;    N = 256;  n0 = (y - 36) * 64; }
  else             { W = Wo; Wt = Wot;                            N = 2048; n0 = (y - 40) * 64; }
  const int k0 = blockIdx.x * 64;
  const int t = threadIdx.x;
  const int r4 = t >> 6, c = t & 63;
#pragma unroll
  for (int p = 0; p < 16; ++p) {
    int r = p * 4 + r4;
    T[r][c] = W[(size_t)(k0 + r) * N + n0 + c];
  }
  __syncthreads();
#pragma unroll
  for (int p = 0; p < 16; ++p) {
    int r = p * 4 + r4;
    Wt[(size_t)(n0 + r) * 2048 + k0 + c] = f2bf(T[c][r]);
  }
}

// ---------- V slice of QKV[4096][2560] -> Vt[(b*2+g)*128+d][2048] ----------
__global__ __launch_bounds__(256) void tv_kernel(const unsigned short* __restrict__ V,
                                                 unsigned short* __restrict__ Vt) {
  __shared__ unsigned short T[64][68];
  const int t0 = blockIdx.x * 64;
  const int d0 = blockIdx.y * 64;
  const int t = threadIdx.x;
  const int r4 = t >> 6, c = t & 63;
#pragma unroll
  for (int p = 0; p < 16; ++p) {
    int r = p * 4 + r4;
    T[r][c] = V[(size_t)(t0 + r) * 2560 + 2304 + d0 + c];
  }
  __syncthreads();
  const int b = t0 >> 11;
  const int tl = t0 & 2047;
#pragma unroll
  for (int p = 0; p < 16; ++p) {
    int dr = p * 4 + r4;
    int dg = d0 + dr;
    int g = dg >> 7, dl = dg & 127;
    Vt[(size_t)((b * 2 + g) * 128 + dl) * 2048 + tl + c] = T[c][dr];
  }
}

// ---------- GEMM: C[M][N] = A[M][K] * Bt[N][K]^T (m97-style) ----------
template <bool FP32OUT>
__global__ __launch_bounds__(256) void gemm_bt_kernel(const unsigned short* __restrict__ A,
                                                      const unsigned short* __restrict__ Bt,
                                                      void* __restrict__ Cout,
                                                      int K, int lda, int ldb, int ldc,
                                                      float scale, int nscale) {
  __shared__ __align__(16) unsigned short As[128 * 64];
  __shared__ __align__(16) unsigned short Bs[128 * 64];
  const int m0 = blockIdx.x * 128, n0 = blockIdx.y * 128;
  const int t = threadIdx.x;
  const int w = t >> 6, lane = t & 63;
  const int l15 = lane & 15, quad = lane >> 4;
  const int wm = (w >> 1) * 64, wn = (w & 1) * 64;

  const int srow = lane >> 3;
  const int sgl = (lane & 7) ^ srow;

  f32x4 acc[4][4] = {};

  for (int k0 = 0; k0 < K; k0 += 64) {
    __syncthreads();
#pragma unroll
    for (int p = 0; p < 4; ++p) {
      int rowbase = p * 32 + w * 8;
      GLL(&A[(size_t)(m0 + rowbase + srow) * lda + k0 + sgl * 8], &As[rowbase * 64]);
      GLL(&Bt[(size_t)(n0 + rowbase + srow) * ldb + k0 + sgl * 8], &Bs[rowbase * 64]);
    }
    __syncthreads();
#pragma unroll
    for (int kk = 0; kk < 64; kk += 32) {
      const int kg = kk >> 3;
      const int phys = ((kg + quad) ^ (l15 & 7)) * 8;
      bf16x8 af[4], bfr[4];
#pragma unroll
      for (int mt = 0; mt < 4; ++mt)
        af[mt] = *reinterpret_cast<const bf16x8*>(&As[(wm + mt * 16 + l15) * 64 + phys]);
#pragma unroll
      for (int nt = 0; nt < 4; ++nt)
        bfr[nt] = *reinterpret_cast<const bf16x8*>(&Bs[(wn + nt * 16 + l15) * 64 + phys]);
#pragma unroll
      for (int mt = 0; mt < 4; ++mt)
#pragma unroll
        for (int nt = 0; nt < 4; ++nt)
          acc[mt][nt] = __builtin_amdgcn_mfma_f32_16x16x32_bf16(af[mt], bfr[nt], acc[mt][nt], 0, 0, 0);
    }
  }

  const float sc = (n0 < nscale) ? scale : 1.0f;
#pragma unroll
  for (int mt = 0; mt < 4; ++mt) {
#pragma unroll
    for (int reg = 0; reg < 4; ++reg) {
      int row = m0 + wm + mt * 16 + quad * 4 + reg;
#pragma unroll
      for (int nt = 0; nt < 4; ++nt) {
        int col = n0 + wn + nt * 16 + l15;
        float v = acc[mt][nt][reg] * sc;
        if (FP32OUT)
          reinterpret_cast<float*>(Cout)[(size_t)row * ldc + col] = v;
        else
          reinterpret_cast<unsigned short*>(Cout)[(size_t)row * ldc + col] = f2bf(v);
      }
    }
  }
}

// ---------- fused causal GQA flash attention, 4 blocks/CU ----------
// grid (2, 16, 32): block (s,by,bh) handles 64-row q-tiles {by, 31-by},
// K/V in 32-token tiles of parity s -> EXACTLY 33 slots per block.
// 37 KB LDS + <=128 VGPR -> 4 blocks/CU = 4 independent barrier streams/SIMD
// (evidence: 1->2 blocks/CU gave 97->66 us). K & V double-buffered via
// global_load_lds, one barrier per slot. Partials (raw O + l) merged by
// merge_kernel (fixed-max softmax => additive).
#define LDQK 2560
__global__ __launch_bounds__(256, 4) void attn_kernel(const unsigned short* __restrict__ Q,
                                                      const unsigned short* __restrict__ Kg,
                                                      const unsigned short* __restrict__ Vt,
                                                      float* __restrict__ O0,
                                                      unsigned short* __restrict__ O1,
                                                      float* __restrict__ L) {
  __shared__ __align__(16) unsigned short Ks[2][32 * 128];   // [token][d], swizzled
  __shared__ __align__(16) unsigned short Vs[2][128 * 32];   // [d][token], swizzled
  __shared__ __align__(16) unsigned short Pw[4][16 * 40];    // per-wave P, pitch 40

  const int s  = blockIdx.x;            // k-parity
  const int by = blockIdx.y;            // 0..15
  const int hh = blockIdx.z & 15;
  const int b  = blockIdx.z >> 4;
  const int g  = hh >> 3;
  const int t  = threadIdx.x;
  const int wg = t >> 6, lane = t & 63;
  const int l15 = lane & 15, quad = lane >> 4;

  const unsigned short* Kbase = Kg + (size_t)b * 2048 * LDQK + g * 128;
  const unsigned short* Vbase = Vt + (size_t)(b * 2 + g) * 128 * 2048;

  // K staging: 32 rows x 128 d. per GLL p: rows wg*4 + p*16 + (lane>>4)
  const int k_r = lane >> 4;            // 0..3
  const int k_g = lane & 15;            // phys group
  // V staging: 128 rows x 32 tok. per GLL p: rows wg*16 + p*64 + (lane>>2)
  const int v_r = lane >> 2;            // 0..15
  const int v_g = lane & 3;             // phys group

  auto issueK = [&](int tile, int buf) {
    const unsigned short* kb = Kbase + (size_t)(tile * 32) * LDQK;
#pragma unroll
    for (int p = 0; p < 2; ++p) {
      int rowbase = p * 16 + wg * 4;
      int row = rowbase + k_r;
      int gl = k_g ^ (row & 15);
      GLL(&kb[(size_t)row * LDQK + gl * 8], &Ks[buf][rowbase * 128]);
    }
  };
  auto issueV = [&](int tile, int buf) {
    const unsigned short* vb = Vbase + tile * 32;
#pragma unroll
    for (int p = 0; p < 2; ++p) {
      int rowbase = p * 64 + wg * 16;
      int row = rowbase + v_r;
      int gl = v_g ^ (row & 3);
      GLL(&vb[(size_t)row * 2048 + gl * 8], &Vs[buf][rowbase * 32]);
    }
  };

  int pb = 0;
  issueK(s, 0);
  issueV(s, 0);

  for (int ph = 0; ph < 2; ++ph) {
    const int qt = ph ? (31 - by) : by;

    // Q fragments: wave owns rows qt*64 + wg*16 + l15
    bf16x8 qf[4];
    {
      int qrow = qt * 64 + wg * 16 + l15;
      const unsigned short* qp = &Q[(size_t)(b * 2048 + qrow) * LDQK + hh * 128 + quad * 8];
#pragma unroll
      for (int dk = 0; dk < 4; ++dk)
        qf[dk] = *reinterpret_cast<const bf16x8*>(qp + dk * 32);
    }

    f32x4 o[8] = {};
    float l_run[4] = {};

    for (int j = 0; j <= qt; ++j) {
      const int tile = 2 * j + s;
      __syncthreads();   // drains GLLs issued last slot; fences buffer reuse
      const int cur = pb, nxt = pb ^ 1;

      if (j < qt) {
        issueK(tile + 2, nxt);
        issueV(tile + 2, nxt);
      } else if (ph == 0) {
        issueK(s, nxt);
        issueV(s, nxt);
      }

      // S = Q K^T   (16 rows x 32 tok per wave)
      f32x4 sc[2] = {};
#pragma unroll
      for (int nt = 0; nt < 2; ++nt) {
#pragma unroll
        for (int dk = 0; dk < 4; ++dk) {
          int phys = (dk * 4 + quad) ^ l15;
          bf16x8 kf = *reinterpret_cast<const bf16x8*>(&Ks[cur][(nt * 16 + l15) * 128 + phys * 8]);
          sc[nt] = __builtin_amdgcn_mfma_f32_16x16x32_bf16(qf[dk], kf, sc[nt], 0, 0, 0);
        }
      }
      if (j == qt) {   // diagonal-overlapping tile: causal mask
#pragma unroll
        for (int nt = 0; nt < 2; ++nt) {
          int kcol = tile * 32 + nt * 16 + l15;
#pragma unroll
          for (int reg = 0; reg < 4; ++reg) {
            int qr = qt * 64 + wg * 16 + quad * 4 + reg;
            if (kcol > qr) sc[nt][reg] = -1e30f;
          }
        }
      }
      // fixed-max softmax: p = e^{s-16}
#pragma unroll
      for (int nt = 0; nt < 2; ++nt)
#pragma unroll
        for (int reg = 0; reg < 4; ++reg) {
          float p = __builtin_exp2f(__builtin_fmaf(sc[nt][reg], 1.44269504f, -23.08312064f));
          l_run[reg] += p;
          Pw[wg][(quad * 4 + reg) * 40 + nt * 16 + l15] = f2bf(p);
        }

      // O += P V  (single K=32 step; wave-local P)
      bf16x8 pf = *reinterpret_cast<const bf16x8*>(&Pw[wg][l15 * 40 + quad * 8]);
#pragma unroll
      for (int dt = 0; dt < 8; ++dt) {
        int phys = quad ^ (l15 & 3);
        bf16x8 vf = *reinterpret_cast<const bf16x8*>(&Vs[cur][(dt * 16 + l15) * 32 + phys * 8]);
        o[dt] = __builtin_amdgcn_mfma_f32_16x16x32_bf16(pf, vf, o[dt], 0, 0, 0);
      }
      pb ^= 1;
    }

    // reduce l over the 16 replicated lanes; store raw partials
#pragma unroll
    for (int off = 1; off <= 8; off <<= 1)
#pragma unroll
      for (int reg = 0; reg < 4; ++reg)
        l_run[reg] += __shfl_xor(l_run[reg], off);

#pragma unroll
    for (int reg = 0; reg < 4; ++reg) {
      int row = wg * 16 + quad * 4 + reg;
      size_t base = (size_t)(b * 2048 + qt * 64 + row) * 2048 + hh * 128;
      if (s == 0) {
#pragma unroll
        for (int dt = 0; dt < 8; ++dt)
          O0[base + dt * 16 + l15] = o[dt][reg];
      } else {
#pragma unroll
        for (int dt = 0; dt < 8; ++dt)
          O1[base + dt * 16 + l15] = f2bf(o[dt][reg]);
      }
      if (l15 == 0)
        L[(size_t)s * 65536 + (size_t)(b * 2048 + qt * 64 + row) * 16 + hh] = l_run[reg];
    }
  }
}

// ---------- merge: Y = (O0 + O1) / (l0 + l1), bf16, in-place over O1 ----------
__global__ __launch_bounds__(256) void merge_kernel(const float* __restrict__ O0,
                                                    unsigned short* __restrict__ O1,
                                                    const float* __restrict__ L) {
  int i4 = blockIdx.x * 256 + threadIdx.x;   // 4 elems each
  int e = i4 << 2;
  int tr = e >> 11;              // token row 0..4095
  int hh = (e >> 7) & 15;        // head
  float l = L[tr * 16 + hh] + L[65536 + tr * 16 + hh];
  float inv = 1.0f / l;
  float4 a = reinterpret_cast<const float4*>(O0)[i4];
  ushort4 u = reinterpret_cast<const ushort4*>(O1)[i4];
  ushort4 r;
  r.x = f2bf((a.x + bf2f(u.x)) * inv);
  r.y = f2bf((a.y + bf2f(u.y)) * inv);
  r.z = f2bf((a.z + bf2f(u.z)) * inv);
  r.w = f2bf((a.w + bf2f(u.w)) * inv);
  reinterpret_cast<ushort4*>(O1)[i4] = r;
}

extern "C" void kernel_launch(void* const* d_in, const int* in_sizes, int n_in,
                              void* d_out, int out_size, void* d_ws, size_t ws_size,
                              hipStream_t stream) {
  const float* x  = (const float*)d_in[0];
  const float* Wq = (const float*)d_in[1];
  const float* Wk = (const float*)d_in[2];
  const float* Wv = (const float*)d_in[3];
  const float* Wo = (const float*)d_in[4];

  char* ws = (char*)d_ws;
  unsigned short* xb    = (unsigned short*)(ws + 0);          // 16 MB (reused: O1/Y)
  unsigned short* Wqkvt = (unsigned short*)(ws + 16777216);   // 10.5 MB
  unsigned short* Wot   = (unsigned short*)(ws + 27262976);   // 8 MB
  unsigned short* QKVb  = (unsigned short*)(ws + 35651584);   // 20 MB
  unsigned short* Vtb   = (unsigned short*)(ws + 56623104);   // 2 MB
  float*          Lb    = (float*)(ws + 58720256);            // 512 KB: [2][4096][16]
  unsigned short* Yb    = xb;

  cast_kernel<<<8192, 256, 0, stream>>>(x, xb, 2097152);
  tcast_all_kernel<<<dim3(32, 72), 256, 0, stream>>>(Wq, Wk, Wv, Wo, Wqkvt, Wot);

  const float qscale = 0.08838834764831845f;  // 1/sqrt(128), folded into Q
  gemm_bt_kernel<false><<<dim3(32, 20), 256, 0, stream>>>(xb, Wqkvt, QKVb,
                                                          2048, 2048, 2048, 2560, qscale, 2048);
  tv_kernel<<<dim3(64, 4), 256, 0, stream>>>(QKVb, Vtb);
  // attention partials: O0 fp32 -> d_out (scratch until final gemm), O1 bf16 -> xb
  attn_kernel<<<dim3(2, 16, 32), 256, 0, stream>>>(QKVb, QKVb + 2048, Vtb,
                                                   (float*)d_out, Yb, Lb);
  merge_kernel<<<8192, 256, 0, stream>>>((const float*)d_out, Yb, Lb);
  gemm_bt_kernel<true><<<dim3(32, 16), 256, 0, stream>>>(Yb, Wot, d_out,
                                                         2048, 2048, 2048, 2048, 1.0f, 0);
}